// Round 1
// baseline (7176.089 us; speedup 1.0000x reference)
//
#include <hip/hip_runtime.h>

#define Bsz 1024
#define Tn  200
#define Dd  64
#define Ld  256
#define Hd  256

#define ROWS   16          // batch rows per workgroup -> 64 WGs
#define NWAVE  8           // waves per WG (512 threads)
#define NTILE  2           // 16-col output tiles per wave (8*2*16 = 256 cols)
#define SA     264         // bf16 row stride for activation LDS
#define SX     72          // bf16 row stride for x tile

typedef __attribute__((ext_vector_type(8))) short  short8;
typedef __attribute__((ext_vector_type(4))) float  floatx4;

// workspace layout (bytes)
#define OFF_W1R  0                         // W1h per-wave reg layout       131072
#define OFF_W1L  (OFF_W1R + Ld*Ld*2)       // fp32 last col of W1             1024
#define OFF_W2R  (OFF_W1L + Hd*4)          // W2 per-wave reg layout        131072
#define OFF_W3R  (OFF_W2R + Hd*Hd*2)       // W3 per-wave reg layout        131072
#define OFF_WIHR (OFF_W3R + Ld*Hd*2)       // Wih per-wave layout            98304
#define OFF_WHHR (OFF_WIHR + 3*Ld*Dd*2)    // Whh per-wave layout           393216
#define OFF_W13R (OFF_WHHR + 3*Ld*Ld*2)    // W13 = W1h@W3 per-wave layout  131072
#define OFF_C13  (OFF_W13R + Hd*Ld*2)      // fp32 c13 = W1h@b3               1024

__device__ __forceinline__ short f2bf(float f) {       // RNE (prep only)
    union { float f; unsigned u; } v; v.f = f;
    unsigned r = v.u + 0x7fffu + ((v.u >> 16) & 1u);
    return (short)(r >> 16);
}
__device__ __forceinline__ short f2bh(float f) {       // cheap round-half-up (hot path)
    union { float f; unsigned u; } v; v.f = f;
    return (short)((v.u + 0x8000u) >> 16);
}
__device__ __forceinline__ float sig_(float x) {
    float e = __expf(-x);
    return __builtin_amdgcn_rcpf(1.f + e);
}
__device__ __forceinline__ float tanh_(float x) {
    float e = __expf(2.f * x);
    return 1.f - 2.f * __builtin_amdgcn_rcpf(e + 1.f);
}
__device__ __forceinline__ floatx4 mfma_(short8 a, short8 b, floatx4 c) {
    return __builtin_amdgcn_mfma_f32_16x16x32_bf16(a, b, c, 0, 0, 0);
}

// ---------------- weight prep: fp32 -> bf16, reordered layouts ----------------
__global__ void prep_kernel(const float* __restrict__ Wih,
                            const float* __restrict__ Whh,
                            const float* __restrict__ W1,
                            const float* __restrict__ W2,
                            const float* __restrict__ W3,
                            const float* __restrict__ b3,
                            char* __restrict__ ws)
{
    short* w1r  = (short*)(ws + OFF_W1R);
    float* w1l  = (float*)(ws + OFF_W1L);
    short* w2r  = (short*)(ws + OFF_W2R);
    short* w3r  = (short*)(ws + OFF_W3R);
    short* wihr = (short*)(ws + OFF_WIHR);
    short* whhr = (short*)(ws + OFF_WHHR);
    short* w13r = (short*)(ws + OFF_W13R);
    float* c13  = (float*)(ws + OFF_C13);
    const int i0 = blockIdx.x * blockDim.x + threadIdx.x;
    const int stride = gridDim.x * blockDim.x;

    // W1R/W2R/W3R: idx = (((wv*2+jt)*8+ks)*64 + lane)*8 + jj
    for (int idx = i0; idx < Hd*Hd; idx += stride) {
        int jj = idx & 7, t = idx >> 3;
        int lane = t & 63; t >>= 6;
        int ks = t & 7; t >>= 3;
        int jt = t & 1, wv = t >> 1;
        int c16 = lane & 15, quad = lane >> 4;
        int col = wv*32 + jt*16 + c16, k = ks*32 + quad*8 + jj;
        w1r[idx] = f2bf(W1[col*(Ld+1) + k]);
        w2r[idx] = f2bf(W2[col*Hd + k]);
        w3r[idx] = f2bf(W3[col*Hd + k]);
    }
    for (int i = i0; i < Hd; i += stride) w1l[i] = W1[i*(Ld+1) + Ld];

    // W13R: W13[col][k] = sum_j W1h[col][j] * W3[j][k]   (fused L3->L1 matrix)
    for (int idx = i0; idx < Hd*Ld; idx += stride) {
        int jj = idx & 7, t = idx >> 3;
        int lane = t & 63; t >>= 6;
        int ks = t & 7; t >>= 3;
        int jt = t & 1, wv = t >> 1;
        int c16 = lane & 15, quad = lane >> 4;
        int col = wv*32 + jt*16 + c16, k = ks*32 + quad*8 + jj;
        float acc = 0.f;
        for (int j = 0; j < Ld; ++j)
            acc += W1[col*(Ld+1) + j] * W3[j*Hd + k];
        w13r[idx] = f2bf(acc);
    }
    // c13[c] = sum_j W1h[c][j] * b3[j]
    for (int c = i0; c < Hd; c += stride) {
        float a = 0.f;
        for (int j = 0; j < Ld; ++j) a += W1[c*(Ld+1) + j] * b3[j];
        c13[c] = a;
    }

    // WIHR: idx = ((((g*8+wv)*2+jt)*2+ks)*64 + lane)*8 + jj   (ks<2)
    for (int idx = i0; idx < 3*Ld*Dd; idx += stride) {
        int jj = idx & 7, t = idx >> 3;
        int lane = t & 63; t >>= 6;
        int ks = t & 1; t >>= 1;
        int jt = t & 1; t >>= 1;
        int wv = t & 7, g = t >> 3;
        int c16 = lane & 15, quad = lane >> 4;
        int col = wv*32 + jt*16 + c16, k = ks*32 + quad*8 + jj;
        wihr[idx] = f2bf(Wih[(g*Ld + col)*Dd + k]);
    }
    // WHHR: idx = ((((g*8+wv)*2+jt)*8+ks)*64 + lane)*8 + jj
    for (int idx = i0; idx < 3*Ld*Ld; idx += stride) {
        int jj = idx & 7, t = idx >> 3;
        int lane = t & 63; t >>= 6;
        int ks = t & 7; t >>= 3;
        int jt = t & 1; t >>= 1;
        int wv = t & 7, g = t >> 3;
        int c16 = lane & 15, quad = lane >> 4;
        int col = wv*32 + jt*16 + c16, k = ks*32 + quad*8 + jj;
        whhr[idx] = f2bf(Whh[(g*Ld + col)*Ld + k]);
    }
}

// ---------------- persistent ODE-RNN kernel ----------------
__global__ __launch_bounds__(NWAVE*64, 2) void odernn_kernel(
    const float* __restrict__ x,    const float* __restrict__ tarr,
    const float* __restrict__ mask,
    const float* __restrict__ b_ih, const float* __restrict__ b_hh,
    const float* __restrict__ b1v,  const float* __restrict__ b2v,
    const float* __restrict__ b3v,  const char* __restrict__ ws,
    float* __restrict__ out)
{
    __shared__ __attribute__((aligned(16))) short ays[ROWS*SA];
    __shared__ __attribute__((aligned(16))) short bu [ROWS*SA];
    __shared__ __attribute__((aligned(16))) short cv [ROWS*SA];
    __shared__ __attribute__((aligned(16))) short xb [ROWS*SX];
    __shared__ float maskv[ROWS];

    const short* WIHR = (const short*)(ws + OFF_WIHR);
    const short* WHHR = (const short*)(ws + OFF_WHHR);
    const short* W1R  = (const short*)(ws + OFF_W1R);
    const short* W3R  = (const short*)(ws + OFF_W3R);
    const float* W1l  = (const float*)(ws + OFF_W1L);
    const float* C13  = (const float*)(ws + OFF_C13);

    const int tid  = threadIdx.x;
    const int wv   = tid >> 6;
    const int lane = tid & 63;
    const int quad = lane >> 4;
    const int c16  = lane & 15;
    const int koff = quad * 8;
    const int b0   = blockIdx.x * ROWS;
    const int aoff = c16*SA + koff;         // A-frag base (shorts)

    // register-resident weights: W2 and W13 only (the 16x/timestep ones)
    // W1h and W3 are used 1x/timestep each -> read from L2 in-loop.
    short8 w2r[NTILE][8], w13r[NTILE][8];
    {
        const short* W2R  = (const short*)(ws + OFF_W2R);
        const short* W13R = (const short*)(ws + OFF_W13R);
#pragma unroll
        for (int jt = 0; jt < NTILE; ++jt)
#pragma unroll
            for (int ks = 0; ks < 8; ++ks) {
                int off = (((wv*NTILE + jt)*8 + ks)*64 + lane)*8;
                w2r[jt][ks]  = *(const short8*)(W2R + off);
                w13r[jt][ks] = *(const short8*)(W13R + off);
            }
    }

    // per-lane loop-invariant columns + biases
    int   ccol[NTILE];
    float b1c[NTILE], b2c[NTILE], b3c[NTILE], w1lc[NTILE], c13c[NTILE];
#pragma unroll
    for (int jt = 0; jt < NTILE; ++jt) {
        int c = wv * (16*NTILE) + jt*16 + c16;
        ccol[jt] = c;
        b1c[jt]  = b1v[c]; b2c[jt] = b2v[c]; b3c[jt] = b3v[c];
        w1lc[jt] = W1l[c]; c13c[jt] = C13[c];
    }

    // fp32 hidden state: lane owns (row=quad*4+i, col=ccol[jt])
    float hreg[NTILE][4];
#pragma unroll
    for (int jt = 0; jt < NTILE; ++jt)
#pragma unroll
        for (int i = 0; i < 4; ++i) hreg[jt][i] = 0.f;

    for (int i = tid; i < ROWS*SA; i += NWAVE*64) ays[i] = 0;  // bf16(h=0)
    __syncthreads();

    for (int t = 0; t < Tn; ++t) {
        // ---- stage x tile + mask ----
        for (int i = tid; i < ROWS*Dd; i += NWAVE*64) {
            int r = i >> 6, d = i & 63;
            xb[r*SX + d] = f2bf(x[((size_t)(b0 + r)*Tn + t)*Dd + d]);
        }
        if (tid < ROWS) maskv[tid] = mask[(size_t)(b0 + tid)*Tn + t];
        __syncthreads();

        // ---- GRU per tile ----
        float hobs_s[NTILE][4];
#pragma unroll
        for (int jt = 0; jt < NTILE; ++jt) {
            floatx4 z4 = {0.f,0.f,0.f,0.f};
            floatx4 ar = z4, az = z4, ain = z4, ahn = z4;
#pragma unroll
            for (int ks = 0; ks < 2; ++ks) {
                short8 a = *(const short8*)&xb[c16*SX + ks*32 + koff];
                const short* p = WIHR + wv*2048 + jt*1024 + ks*512 + lane*8;
                ar  = mfma_(a, *(const short8*)(p),         ar);
                az  = mfma_(a, *(const short8*)(p + 16384), az);
                ain = mfma_(a, *(const short8*)(p + 32768), ain);
            }
#pragma unroll 1
            for (int ks = 0; ks < 8; ++ks) {
                short8 a = *(const short8*)&ays[aoff + ks*32];
                const short* p = WHHR + wv*8192 + jt*4096 + ks*512 + lane*8;
                ar  = mfma_(a, *(const short8*)(p),          ar);
                az  = mfma_(a, *(const short8*)(p + 65536),  az);
                ahn = mfma_(a, *(const short8*)(p + 131072), ahn);
            }
            int c = ccol[jt];
            float birv = b_ih[c]      + b_hh[c];
            float bizv = b_ih[Ld+c]   + b_hh[Ld+c];
            float binv = b_ih[2*Ld+c];
            float bhnv = b_hh[2*Ld+c];
#pragma unroll
            for (int i = 0; i < 4; ++i) {
                float hold = hreg[jt][i];
                float r = sig_(ar[i] + birv);
                float z = sig_(az[i] + bizv);
                float n = tanh_(ain[i] + binv + r*(ahn[i] + bhnv));
                float hnew = (1.f - z)*n + z*hold;
                float m = maskv[quad*4 + i];
                hobs_s[jt][i] = m*hnew + (1.f - m)*hold;
            }
        }
        __syncthreads();   // all waves finished reading ays

        // ---- write-back h_obs: state regs + bf16 mirror + global out ----
#pragma unroll
        for (int jt = 0; jt < NTILE; ++jt)
#pragma unroll
            for (int i = 0; i < 4; ++i) {
                int row = quad*4 + i;
                float hobs = hobs_s[jt][i];
                hreg[jt][i] = hobs;
                ays[row*SA + ccol[jt]] = f2bh(hobs);
                out[((size_t)(b0+row)*Tn + t)*Ld + ccol[jt]] = hobs;
            }
        __syncthreads();

        if (t == Tn - 1) break;   // last step: GRU only (h_fin)

        // ---- init hW1 = h_obs @ W1h^T (B-frags from L2, 1x per timestep) ----
        float hW1[NTILE][4];
        {
            floatx4 acc[NTILE];
#pragma unroll
            for (int jt = 0; jt < NTILE; ++jt) { floatx4 z4 = {0.f,0.f,0.f,0.f}; acc[jt] = z4; }
#pragma unroll 2
            for (int ks = 0; ks < 8; ++ks) {
                short8 a = *(const short8*)&ays[aoff + ks*32];
                const short* p = W1R + wv*8192 + ks*512 + lane*8;
#pragma unroll
                for (int jt = 0; jt < NTILE; ++jt)
                    acc[jt] = mfma_(a, *(const short8*)(p + jt*4096), acc[jt]);
            }
#pragma unroll
            for (int jt = 0; jt < NTILE; ++jt)
#pragma unroll
                for (int i = 0; i < 4; ++i) hW1[jt][i] = acc[jt][i];
        }

        const float t0v = tarr[t];
        const float t1v = tarr[t+1];
        const float dt  = (t1v - t0v) * 0.25f;
        const float dt6 = dt * (1.f/6.f);

        float Vtot[NTILE][4];
#pragma unroll
        for (int jt = 0; jt < NTILE; ++jt)
#pragma unroll
            for (int i = 0; i < 4; ++i) Vtot[jt][i] = 0.f;

#pragma unroll 1
        for (int sub = 0; sub < 4; ++sub) {
            const float tt = t0v + dt * (float)sub;
            float z1[NTILE][4], vacc[NTILE][4];
#pragma unroll
            for (int jt = 0; jt < NTILE; ++jt)
#pragma unroll
                for (int i = 0; i < 4; ++i) {
                    z1[jt][i]   = hW1[jt][i] + tt*w1lc[jt] + b1c[jt];
                    vacc[jt][i] = 0.f;
                }

#pragma unroll 1
            for (int s = 0; s < 4; ++s) {
                // ---- u = tanh(z1) -> bu ----
#pragma unroll
                for (int jt = 0; jt < NTILE; ++jt)
#pragma unroll
                    for (int i = 0; i < 4; ++i)
                        bu[(quad*4+i)*SA + ccol[jt]] = f2bh(tanh_(z1[jt][i]));
                __syncthreads();

                // ---- v = tanh(u @ W2^T + b2), W2 in regs ----
                floatx4 acc[NTILE];
#pragma unroll
                for (int jt = 0; jt < NTILE; ++jt) { floatx4 z4 = {0.f,0.f,0.f,0.f}; acc[jt] = z4; }
#pragma unroll
                for (int ks = 0; ks < 8; ++ks) {
                    short8 a = *(const short8*)&bu[aoff + ks*32];
#pragma unroll
                    for (int jt = 0; jt < NTILE; ++jt)
                        acc[jt] = mfma_(a, w2r[jt][ks], acc[jt]);
                }
                const float wst = (s==1 || s==2) ? 2.f : 1.f;
#pragma unroll
                for (int jt = 0; jt < NTILE; ++jt)
#pragma unroll
                    for (int i = 0; i < 4; ++i) {
                        float v = tanh_(acc[jt][i] + b2c[jt]);
                        vacc[jt][i] += wst * v;
                        float sv = (s < 3) ? v : vacc[jt][i];
                        cv[(quad*4+i)*SA + ccol[jt]] = f2bh(sv);
                    }
                __syncthreads();

                // ---- fused L3->L1: p = v(acc) @ W13^T, W13 in regs ----
#pragma unroll
                for (int jt = 0; jt < NTILE; ++jt) { floatx4 z4 = {0.f,0.f,0.f,0.f}; acc[jt] = z4; }
#pragma unroll
                for (int ks = 0; ks < 8; ++ks) {
                    short8 a = *(const short8*)&cv[aoff + ks*32];
#pragma unroll
                    for (int jt = 0; jt < NTILE; ++jt)
                        acc[jt] = mfma_(a, w13r[jt][ks], acc[jt]);
                }
                if (s < 3) {
                    const float coef = (s==2) ? dt : 0.5f*dt;
                    const float tvn  = (s==2) ? (tt+dt) : (tt+0.5f*dt);
#pragma unroll
                    for (int jt = 0; jt < NTILE; ++jt)
#pragma unroll
                        for (int i = 0; i < 4; ++i)
                            z1[jt][i] = hW1[jt][i] + coef*(acc[jt][i] + c13c[jt])
                                      + tvn*w1lc[jt] + b1c[jt];
                } else {
                    // hW1' = hW1 + dt/6 * (vacc @ W13^T + 6*c13)
#pragma unroll
                    for (int jt = 0; jt < NTILE; ++jt)
#pragma unroll
                        for (int i = 0; i < 4; ++i) {
                            hW1[jt][i] += dt6*acc[jt][i] + dt*c13c[jt];
                            Vtot[jt][i] += vacc[jt][i];
                        }
                }
            } // stages
        } // substeps

        // ---- h update: h += dt/6 * (Vtot @ W3^T) + (t1-t0)*b3, W3 from L2 ----
#pragma unroll
        for (int jt = 0; jt < NTILE; ++jt)
#pragma unroll
            for (int i = 0; i < 4; ++i)
                bu[(quad*4+i)*SA + ccol[jt]] = f2bh(Vtot[jt][i]);
        __syncthreads();
        {
            floatx4 acc[NTILE];
#pragma unroll
            for (int jt = 0; jt < NTILE; ++jt) { floatx4 z4 = {0.f,0.f,0.f,0.f}; acc[jt] = z4; }
#pragma unroll 2
            for (int ks = 0; ks < 8; ++ks) {
                short8 a = *(const short8*)&bu[aoff + ks*32];
                const short* p = W3R + wv*8192 + ks*512 + lane*8;
#pragma unroll
                for (int jt = 0; jt < NTILE; ++jt)
                    acc[jt] = mfma_(a, *(const short8*)(p + jt*4096), acc[jt]);
            }
            const float fdt = t1v - t0v;   // 4*dt
#pragma unroll
            for (int jt = 0; jt < NTILE; ++jt)
#pragma unroll
                for (int i = 0; i < 4; ++i) {
                    float hn = hreg[jt][i] + dt6*acc[jt][i] + fdt*b3c[jt];
                    hreg[jt][i] = hn;
                    ays[(quad*4+i)*SA + ccol[jt]] = f2bh(hn);
                }
        }
        // next-iteration x-stage barrier orders these ays writes before GRU reads
    } // t
}

extern "C" void kernel_launch(void* const* d_in, const int* in_sizes, int n_in,
                              void* d_out, int out_size, void* d_ws, size_t ws_size,
                              hipStream_t stream) {
    (void)in_sizes; (void)n_in; (void)out_size; (void)ws_size;
    const float* x    = (const float*)d_in[0];
    const float* tarr = (const float*)d_in[1];
    const float* mask = (const float*)d_in[2];
    const float* Wih  = (const float*)d_in[3];
    const float* Whh  = (const float*)d_in[4];
    const float* bih  = (const float*)d_in[5];
    const float* bhh  = (const float*)d_in[6];
    const float* W1   = (const float*)d_in[7];
    const float* b1   = (const float*)d_in[8];
    const float* W2   = (const float*)d_in[9];
    const float* b2   = (const float*)d_in[10];
    const float* W3   = (const float*)d_in[11];
    const float* b3   = (const float*)d_in[12];
    float* out = (float*)d_out;
    char*  ws  = (char*)d_ws;

    hipLaunchKernelGGL(prep_kernel, dim3(256), dim3(256), 0, stream,
                       Wih, Whh, W1, W2, W3, b3, ws);
    hipLaunchKernelGGL(odernn_kernel, dim3(Bsz/ROWS), dim3(NWAVE*64), 0, stream,
                       x, tarr, mask, bih, bhh, b1, b2, b3, ws, out);
}